// Round 1
// baseline (465.307 us; speedup 1.0000x reference)
//
#include <hip/hip_runtime.h>
#include <math.h>

#define NPTS 65536

using half8   = __attribute__((ext_vector_type(8))) _Float16;
using half4   = __attribute__((ext_vector_type(4))) _Float16;
using floatx4 = __attribute__((ext_vector_type(4))) float;

// ---------------------------------------------------------------------------
// k_prep: weights -> f16 [64 d][1024 kc'] with kc' = c*16 + k (k=15 row zero);
//         features -> f16 table featH[N][64]
// ---------------------------------------------------------------------------
__global__ __launch_bounds__(256) void k_prep(
    const float* __restrict__ ow, const float* __restrict__ w,
    const float* __restrict__ feat,
    _Float16* __restrict__ owt, _Float16* __restrict__ wt,
    _Float16* __restrict__ featH)
{
  int b = blockIdx.x;
  if (b < 256) {                       // 256*256 == 65536 == 64*1024
    int i = b * 256 + threadIdx.x;
    int d = i >> 10, kc = i & 1023, c = kc >> 4, k = kc & 15;
    owt[i] = (k < 15 && d < 60) ? (_Float16)ow[(k * 64 + c) * 60 + d] : (_Float16)0.f;
    wt[i]  = (k < 15) ? (_Float16)w[(k * 64 + c) * 64 + d] : (_Float16)0.f;
  } else {                             // 4096*256 == 1048576 == N*64/4
    int j = (b - 256) * 256 + threadIdx.x;
    float4 f = ((const float4*)feat)[j];
    half4 h = {(_Float16)f.x, (_Float16)f.y, (_Float16)f.z, (_Float16)f.w};
    ((half4*)featH)[j] = h;
  }
}

// ---------------------------------------------------------------------------
// Fused deformable KPConv. 16 pts/block, 4 waves x 4 pts.
// MFMA covers neighbors 0..31 (fT channel index bit-rotated f(c)=((c&7)<<3)|(c>>3)
// so transpose b32 stores are 2-way/bank == conflict-free); neighbors 32,33 via
// VALU rank-2 (fx2 + ds_bpermute). GEMMs run in 4 quarter-K phases (wfh = one
// quarter = 8.4 KB) with ct1..ct3 accumulators held in registers, so total LDS
// < 40 KB -> 4 blocks/CU (__launch_bounds__(256,4)).
// Per-channel batch stats fused into the GEMM1 epilogue (atomicAdd).
// ---------------------------------------------------------------------------
__global__ __launch_bounds__(256, 4) void k_fused(
    const float* __restrict__ query, const float* __restrict__ support,
    const int* __restrict__ nidx, const _Float16* __restrict__ featH,
    const float* __restrict__ kpts, const float* __restrict__ obias,
    const _Float16* __restrict__ owt, const _Float16* __restrict__ wt,
    float* __restrict__ outx, float* __restrict__ stats)
{
  __shared__ float4                 np4[16][34];   // (dx,dy,dz,|np|^2)
  __shared__ unsigned short         sidx[16][34];
  __shared__ __align__(16) _Float16 fT[4][64 * 32];  // per-wave, nbr 0..31
  __shared__ unsigned int           fx2[4][64];      // per-wave, (f32,f33) per c
  __shared__ __align__(16) _Float16 wfh[16 * 264];   // [pt][c_lo*16+k], quarter-K
  __shared__ float                  dk[16][60];      // def_kp(45)+mod(15)

  const int tid  = threadIdx.x;
  const int wave = tid >> 6, lane = tid & 63;
  const int quad = lane >> 4, mm = lane & 15;
  const int base = blockIdx.x * 16;
  _Float16* fTw = fT[wave];
  unsigned int* fTw32 = (unsigned int*)fTw;
  unsigned int* fx2w = fx2[wave];
  const floatx4 fz = {0.f, 0.f, 0.f, 0.f};
  const int me = (mm < 15) ? mm : 14;   // row 15 of conv A is discarded

  // ---- stage neighbor displacements (+|np|^2) + indices ----
  for (int s = tid; s < 544; s += 256) {
    int pt = s / 34, a = s - pt * 34;
    int n = base + pt;
    int id = nidx[n * 34 + a];
    float dx = support[id * 3 + 0] - query[n * 3 + 0];
    float dy = support[id * 3 + 1] - query[n * 3 + 1];
    float dz = support[id * 3 + 2] - query[n * 3 + 2];
    float4 q = {dx, dy, dz, dx * dx + dy * dy + dz * dz};
    np4[pt][a] = q;
    sidx[pt][a] = (unsigned short)id;
  }
  __syncthreads();

  // ---- gather loads (17 row-pairs x 8 chunks = 136 tasks) ----
  auto load_g = [&](int pl, uint4* g0, uint4* g1) {
    #pragma unroll
    for (int it = 0; it < 3; ++it) {
      int task = it * 64 + lane;
      if (task < 136) {
        int rp = task >> 3, ch = task & 7;
        int i0 = (int)sidx[pl][2 * rp], i1 = (int)sidx[pl][2 * rp + 1];
        g0[it] = *(const uint4*)(featH + i0 * 64 + ch * 8);
        g1[it] = *(const uint4*)(featH + i1 * 64 + ch * 8);
      }
    }
  };
  // ---- transpose staged regs -> fTw (rp<16) / fx2w (rp==16) ----
  // channel index stored through f(c) = ((c&7)<<3)|(c>>3): write banks become
  // (ch&1)*16 + pc*4 + o -> exactly 2 lanes/bank (free), read stays at b128 floor.
  auto transpose_g = [&](const uint4* g0, const uint4* g1) {
    #pragma unroll
    for (int it = 0; it < 3; ++it) {
      int task = it * 64 + lane;
      if (task < 136) {
        int rp = task >> 3, ch = task & 7;
        const uint* p0 = (const uint*)&g0[it];
        const uint* p1 = (const uint*)&g1[it];
        if (rp < 16) {
          int chunk = rp >> 2, o = rp & 3;
          #pragma unroll
          for (int cc = 0; cc < 8; ++cc) {
            int c  = ch * 8 + cc;
            int f  = ((c & 7) << 3) | (c >> 3);      // == cc*8 + ch
            int pc = chunk ^ (((c >> 3) ^ c) & 3);
            uint v = __builtin_amdgcn_perm(p1[cc >> 1], p0[cc >> 1],
                                           (cc & 1) ? 0x07060302u : 0x05040100u);
            fTw32[f * 16 + pc * 4 + o] = v;
          }
        } else {  // rows 32,33 -> fx2 (lo = f32[c], hi = f33[c])
          #pragma unroll
          for (int cc = 0; cc < 8; ++cc) {
            uint v = __builtin_amdgcn_perm(p1[cc >> 1], p0[cc >> 1],
                                           (cc & 1) ? 0x07060302u : 0x05040100u);
            fx2w[ch * 8 + cc] = v;
          }
        }
      }
    }
  };

  // ---- one conv point: 4 MFMA (nbr 0..31) + rank-2 (nbr 32,33), x mod.
  //      writes ct0 to wfh, returns ct1..ct3 in hold3[3] ----
  auto conv_point = [&](int pl, float kx, float ky, float kz, const float* md,
                        floatx4* hold3) {
    float hk = kx * kx + ky * ky + kz * kz;
    half8 a0;
    #pragma unroll
    for (int j = 0; j < 8; ++j) {
      int a = quad * 8 + j;
      float4 q = np4[pl][a];
      float dt = q.x * kx + q.y * ky + q.z * kz;
      float d2 = fmaxf(q.w + hk - 2.f * dt, 0.f);   // |np-kp|^2, clamp fp noise
      float wv = 1.f - 2.f * sqrtf(d2);
      a0[j] = (_Float16)fmaxf(wv, 0.f);
    }
    // rank-2 influence at kp=me, then redistribute to k=quad*4+r via bpermute
    float w32, w33;
    {
      float4 q = np4[pl][32];
      float dt = q.x * kx + q.y * ky + q.z * kz;
      w32 = fmaxf(1.f - 2.f * sqrtf(fmaxf(q.w + hk - 2.f * dt, 0.f)), 0.f);
      q = np4[pl][33];
      dt = q.x * kx + q.y * ky + q.z * kz;
      w33 = fmaxf(1.f - 2.f * sqrtf(fmaxf(q.w + hk - 2.f * dt, 0.f)), 0.f);
    }
    float w32r[4], w33r[4];
    #pragma unroll
    for (int r = 0; r < 4; ++r) {
      int src = (quad * 4 + r) << 2;
      w32r[r] = __int_as_float(__builtin_amdgcn_ds_bpermute(src, __float_as_int(w32)));
      w33r[r] = __int_as_float(__builtin_amdgcn_ds_bpermute(src, __float_as_int(w33)));
    }

    floatx4 acc[4];
    #pragma unroll
    for (int ct = 0; ct < 4; ++ct) {
      int c  = ct * 16 + mm;
      int f  = ((c & 7) << 3) | (c >> 3);
      int pc = quad ^ (((c >> 3) ^ c) & 3);
      half8 b = *(const half8*)(fTw + f * 32 + pc * 8);
      acc[ct] = __builtin_amdgcn_mfma_f32_16x16x32_f16(a0, b, fz, 0, 0, 0);
    }
    #pragma unroll
    for (int ct = 0; ct < 4; ++ct) {
      int c = ct * 16 + mm;
      uint fp = fx2w[c];
      _Float16 lo = __builtin_bit_cast(_Float16, (unsigned short)(fp & 0xffffu));
      _Float16 hi = __builtin_bit_cast(_Float16, (unsigned short)(fp >> 16));
      float flo = (float)lo, fhi = (float)hi;
      #pragma unroll
      for (int r = 0; r < 4; ++r)
        acc[ct][r] = (acc[ct][r] + w32r[r] * flo + w33r[r] * fhi) * md[r];
    }

    _Float16* wp = wfh + pl * 264;
    half4 h = {(_Float16)acc[0][0], (_Float16)acc[0][1],
               (_Float16)acc[0][2], (_Float16)acc[0][3]};
    *(half4*)(wp + mm * 16 + quad * 4) = h;
    hold3[0] = acc[1]; hold3[1] = acc[2]; hold3[2] = acc[3];
  };

  // ---- write one held quarter (ct = idx+1) into wfh ----
  auto write_hold = [&](const floatx4 (*hold)[3], int idx) {
    #pragma unroll
    for (int pp = 0; pp < 4; ++pp) {
      const floatx4& a = hold[pp][idx];
      half4 h = {(_Float16)a[0], (_Float16)a[1], (_Float16)a[2], (_Float16)a[3]};
      *(half4*)(wfh + (wave * 4 + pp) * 264 + mm * 16 + quad * 4) = h;
    }
  };

  // ---- quarter-K GEMM: 8 k-steps vs bmat rows [64][1024], quarter p ----
  auto gemm_q = [&](const _Float16* bmat, int p, floatx4& A, floatx4& B) {
    const _Float16* brow = bmat + (wave * 16 + mm) * 1024 + p * 256;
    const _Float16* arow = wfh + mm * 264;
    #pragma unroll
    for (int k2 = 0; k2 < 8; ++k2) {
      half8 af = *(const half8*)(arow + k2 * 32 + quad * 8);
      half8 bf = *(const half8*)(brow + k2 * 32 + quad * 8);
      if (k2 & 1) B = __builtin_amdgcn_mfma_f32_16x16x32_f16(af, bf, B, 0, 0, 0);
      else        A = __builtin_amdgcn_mfma_f32_16x16x32_f16(af, bf, A, 0, 0, 0);
    }
  };

  uint4 G0[2][3], G1[2][3];
  floatx4 hold[4][3];
  const float one4[4] = {1.f, 1.f, 1.f, 1.f};

  // ================= conv0 (rigid kernel points) =================
  {
    float k0x = kpts[me * 3 + 0], k0y = kpts[me * 3 + 1], k0z = kpts[me * 3 + 2];
    load_g(wave * 4, G0[0], G1[0]);
    #pragma unroll
    for (int pp = 0; pp < 4; ++pp) {
      int pl = wave * 4 + pp;
      if (pp < 3) load_g(pl + 1, G0[(pp + 1) & 1], G1[(pp + 1) & 1]);
      transpose_g(G0[pp & 1], G1[pp & 1]);
      conv_point(pl, k0x, k0y, k0z, one4, hold[pp]);
    }
  }
  load_g(wave * 4, G0[0], G1[0]);   // prefetch conv1 p0 under GEMM0
  __syncthreads();

  // ================= GEMM0 (4 quarter-K phases) -> def_kp + modulations ======
  {
    floatx4 A = fz, B = fz;
    gemm_q(owt, 0, A, B);
    __syncthreads(); write_hold(hold, 0); __syncthreads();
    gemm_q(owt, 1, A, B);
    __syncthreads(); write_hold(hold, 1); __syncthreads();
    gemm_q(owt, 2, A, B);
    __syncthreads(); write_hold(hold, 2); __syncthreads();
    gemm_q(owt, 3, A, B);
    int d = wave * 16 + mm;
    float bv = (d < 60) ? obias[d] : 0.f;
    float kv = (d < 45) ? kpts[d] : 0.f;
    #pragma unroll
    for (int r = 0; r < 4; ++r) {
      int pt = quad * 4 + r;
      float v = A[r] + B[r] + bv;
      if (d < 60)
        dk[pt][d] = (d < 45) ? (kv + 0.5f * v)            // def_kp = kp + f0*EXTENT
                             : (2.f / (1.f + expf(-v)));  // modulation
    }
  }
  __syncthreads();   // dk ready; GEMM0 wfh reads done

  // ================= conv1 (deformed kernel points) =================
  #pragma unroll
  for (int pp = 0; pp < 4; ++pp) {
    int pl = wave * 4 + pp;
    if (pp < 3) load_g(pl + 1, G0[(pp + 1) & 1], G1[(pp + 1) & 1]);
    float kx = dk[pl][me * 3 + 0], ky = dk[pl][me * 3 + 1], kz = dk[pl][me * 3 + 2];
    float md[4];
    #pragma unroll
    for (int r = 0; r < 4; ++r) {
      int k = quad * 4 + r;
      int kk = (k < 15) ? k : 14;                  // keep index in-bounds
      float t = dk[pl][45 + kk];
      md[r] = (k < 15) ? t : 1.f;
    }
    transpose_g(G0[pp & 1], G1[pp & 1]);
    conv_point(pl, kx, ky, kz, md, hold[pp]);
  }
  __syncthreads();

  // ================= GEMM1 (4 quarter-K phases) -> x + fused batch stats =====
  {
    floatx4 A = fz, B = fz;
    gemm_q(wt, 0, A, B);
    __syncthreads(); write_hold(hold, 0); __syncthreads();
    gemm_q(wt, 1, A, B);
    __syncthreads(); write_hold(hold, 1); __syncthreads();
    gemm_q(wt, 2, A, B);
    __syncthreads(); write_hold(hold, 2); __syncthreads();
    gemm_q(wt, 3, A, B);
    int d = wave * 16 + mm;
    float s1 = 0.f, s2 = 0.f;
    #pragma unroll
    for (int r = 0; r < 4; ++r) {
      float v = A[r] + B[r];
      outx[(base + quad * 4 + r) * 64 + d] = v;
      s1 += v; s2 += v * v;
    }
    s1 += __shfl_xor(s1, 16); s2 += __shfl_xor(s2, 16);
    s1 += __shfl_xor(s1, 32); s2 += __shfl_xor(s2, 32);
    if (lane < 16) {
      atomicAdd(&stats[d], s1);
      atomicAdd(&stats[64 + d], s2);
    }
  }
}

// ---------------------------------------------------------------------------
// BN (batch stats, biased var, eps=1e-6) + LeakyReLU(0.1), in-place
// ---------------------------------------------------------------------------
__global__ __launch_bounds__(256) void k_norm(
    float* __restrict__ x, const float* __restrict__ stats,
    const float* __restrict__ gamma, const float* __restrict__ beta)
{
  const int i = blockIdx.x * 256 + threadIdx.x;
  float4 v = ((float4*)x)[i];
  const int c0 = (i * 4) & 63;
  float o[4] = {v.x, v.y, v.z, v.w};
  #pragma unroll
  for (int j = 0; j < 4; ++j) {
    int c = c0 + j;
    float mean = stats[c] * (1.f / NPTS);
    float var  = stats[64 + c] * (1.f / NPTS) - mean * mean;
    float s = rsqrtf(var + 1e-6f) * gamma[c];
    float y = (o[j] - mean) * s + beta[c];
    o[j] = (y >= 0.f) ? y : 0.1f * y;
  }
  float4 rv = {o[0], o[1], o[2], o[3]};
  ((float4*)x)[i] = rv;
}

// ---------------------------------------------------------------------------
extern "C" void kernel_launch(void* const* d_in, const int* in_sizes, int n_in,
                              void* d_out, int out_size, void* d_ws, size_t ws_size,
                              hipStream_t stream)
{
  const float* query   = (const float*)d_in[0];
  const float* support = (const float*)d_in[1];
  const int*   nidx    = (const int*)d_in[2];
  const float* feat    = (const float*)d_in[3];
  const float* weight  = (const float*)d_in[4];
  const float* oweight = (const float*)d_in[5];
  const float* obias   = (const float*)d_in[6];
  const float* gamma   = (const float*)d_in[7];
  const float* beta    = (const float*)d_in[8];
  const float* kpts    = (const float*)d_in[9];
  float* x = (float*)d_out;

  char* ws = (char*)d_ws;
  _Float16* featH = (_Float16*)ws;                  // 8,388,608 B
  _Float16* owt   = (_Float16*)(ws + 8388608);      //   131,072 B
  _Float16* wt    = (_Float16*)(ws + 8519680);      //   131,072 B
  float*    stats = (float*)(ws + 8650752);         //       512 B

  hipMemsetAsync(stats, 0, 512, stream);
  k_prep<<<4352, 256, 0, stream>>>(oweight, weight, feat, owt, wt, featH);
  k_fused<<<4096, 256, 0, stream>>>(query, support, nidx, featH, kpts, obias,
                                    owt, wt, x, stats);
  k_norm<<<4096, 256, 0, stream>>>(x, stats, gamma, beta);
}

// Round 2
// 351.224 us; speedup vs baseline: 1.3248x; 1.3248x over previous
//
#include <hip/hip_runtime.h>
#include <math.h>

#define NPTS 65536

using half8   = __attribute__((ext_vector_type(8))) _Float16;
using half4   = __attribute__((ext_vector_type(4))) _Float16;
using floatx4 = __attribute__((ext_vector_type(4))) float;

// ---------------------------------------------------------------------------
// k_prep: weights -> f16 [64 d][1024 kc'] with kc' = c*16 + k (k=15 row zero);
//         features -> f16 table featH[N][64]. Block 0 also zeroes stats.
// ---------------------------------------------------------------------------
__global__ __launch_bounds__(256) void k_prep(
    const float* __restrict__ ow, const float* __restrict__ w,
    const float* __restrict__ feat,
    _Float16* __restrict__ owt, _Float16* __restrict__ wt,
    _Float16* __restrict__ featH, float* __restrict__ stats)
{
  int b = blockIdx.x;
  if (b < 256) {                       // 256*256 == 65536 == 64*1024
    int i = b * 256 + threadIdx.x;
    int d = i >> 10, kc = i & 1023, c = kc >> 4, k = kc & 15;
    owt[i] = (k < 15 && d < 60) ? (_Float16)ow[(k * 64 + c) * 60 + d] : (_Float16)0.f;
    wt[i]  = (k < 15) ? (_Float16)w[(k * 64 + c) * 64 + d] : (_Float16)0.f;
    if (b == 0 && threadIdx.x < 128) stats[threadIdx.x] = 0.f;
  } else {                             // 4096*256 == 1048576 == N*64/4
    int j = (b - 256) * 256 + threadIdx.x;
    float4 f = ((const float4*)feat)[j];
    half4 h = {(_Float16)f.x, (_Float16)f.y, (_Float16)f.z, (_Float16)f.w};
    ((half4*)featH)[j] = h;
  }
}

// ---------------------------------------------------------------------------
// Fused deformable KPConv. 16 pts/block, 4 waves x 4 pts.
// Key change vs the 205us version: conv0 and conv1 consume IDENTICAL feature
// data, so the MFMA B-fragments are gathered+transposed ONCE (conv0) and kept
// in registers (bfr[4][4], 64 VGPRs) for conv1 -- the second gather pass and
// second transpose are gone. The ct2/3 MFMAs are deferred into GEMM phase B
// (recompute from a0c + bfr; rank-2 fixup recomputed from LDS), replacing the
// 32-reg hold with 16 regs of a0. Rank-2 neighbor (32/33) features live in a
// per-point LDS table fx2s filled once at block start. Batch stats fused into
// the GEMM1 epilogue. LDS 50816 B -> 3 blocks/CU; launch_bounds (256,3) so
// the allocator is NOT capped (round-1 lesson: forced 4 waves/EU -> spills).
// ---------------------------------------------------------------------------
__global__ __launch_bounds__(256, 3) void k_fused(
    const float* __restrict__ query, const float* __restrict__ support,
    const int* __restrict__ nidx, const _Float16* __restrict__ featH,
    const float* __restrict__ kpts, const float* __restrict__ obias,
    const _Float16* __restrict__ owt, const _Float16* __restrict__ wt,
    float* __restrict__ outx, float* __restrict__ stats)
{
  __shared__ float4                 np4[16][34];     // (dx,dy,dz,|np|^2) 8704B
  __shared__ unsigned short         sidx[16][34];    // 1088B
  __shared__ __align__(16) _Float16 fT[4][64 * 32];  // per-wave transpose 16384B
  __shared__ unsigned int           fx2s[16][65];    // (f32,f33) per pt,c 4160B
  __shared__ __align__(16) _Float16 wfh[16 * 520];   // half-K A-panel 16640B
  __shared__ float                  dk[16][60];      // def_kp(45)+mod(15) 3840B

  const int tid  = threadIdx.x;
  const int wave = tid >> 6, lane = tid & 63;
  const int quad = lane >> 4, mm = lane & 15;
  const int base = blockIdx.x * 16;
  _Float16* fTw = fT[wave];
  unsigned int* fTw32 = (unsigned int*)fTw;
  const floatx4 fz = {0.f, 0.f, 0.f, 0.f};
  const int me = (mm < 15) ? mm : 14;   // row 15 of conv A is discarded

  // ---- stage neighbor displacements (+|np|^2) + indices ----
  for (int s = tid; s < 544; s += 256) {
    int pt = s / 34, a = s - pt * 34;
    int n = base + pt;
    int id = nidx[n * 34 + a];
    float dx = support[id * 3 + 0] - query[n * 3 + 0];
    float dy = support[id * 3 + 1] - query[n * 3 + 1];
    float dz = support[id * 3 + 2] - query[n * 3 + 2];
    float4 q = {dx, dy, dz, dx * dx + dy * dy + dz * dz};
    np4[pt][a] = q;
    sidx[pt][a] = (unsigned short)id;
  }
  __syncthreads();

  // ---- rank-2 neighbor (rows 32,33) features -> fx2s[pt][c], once/block ----
  if (tid < 128) {
    int pt = tid >> 3, ch = tid & 7;
    int i0 = (int)sidx[pt][32], i1 = (int)sidx[pt][33];
    uint4 g0 = *(const uint4*)(featH + i0 * 64 + ch * 8);
    uint4 g1 = *(const uint4*)(featH + i1 * 64 + ch * 8);
    const uint* p0 = (const uint*)&g0;
    const uint* p1 = (const uint*)&g1;
    #pragma unroll
    for (int cc = 0; cc < 8; ++cc) {
      uint v = __builtin_amdgcn_perm(p1[cc >> 1], p0[cc >> 1],
                                     (cc & 1) ? 0x07060302u : 0x05040100u);
      fx2s[pt][ch * 8 + cc] = v;
    }
  }
  __syncthreads();

  // ---- gather loads: 16 row-pairs x 8 chunks = 128 tasks, 2 full iters ----
  auto load_g = [&](int pl, uint4* g0, uint4* g1) {
    #pragma unroll
    for (int it = 0; it < 2; ++it) {
      int task = it * 64 + lane;
      int rp = task >> 3, ch = task & 7;
      int i0 = (int)sidx[pl][2 * rp], i1 = (int)sidx[pl][2 * rp + 1];
      g0[it] = *(const uint4*)(featH + i0 * 64 + ch * 8);
      g1[it] = *(const uint4*)(featH + i1 * 64 + ch * 8);
    }
  };
  // ---- transpose staged regs -> fTw; channel rotated f(c)=((c&7)<<3)|(c>>3)
  //      so b32 stores hit 2 lanes/bank (free) ----
  auto transpose_g = [&](const uint4* g0, const uint4* g1) {
    #pragma unroll
    for (int it = 0; it < 2; ++it) {
      int task = it * 64 + lane;
      int rp = task >> 3, ch = task & 7;
      int chunk = rp >> 2, o = rp & 3;
      const uint* p0 = (const uint*)&g0[it];
      const uint* p1 = (const uint*)&g1[it];
      #pragma unroll
      for (int cc = 0; cc < 8; ++cc) {
        int f  = cc * 8 + ch;                       // rotation of c = ch*8+cc
        int pc = chunk ^ ((ch ^ cc) & 3);
        uint v = __builtin_amdgcn_perm(p1[cc >> 1], p0[cc >> 1],
                                       (cc & 1) ? 0x07060302u : 0x05040100u);
        fTw32[f * 16 + pc * 4 + o] = v;
      }
    }
  };

  // ---- influence row for this lane's kernel point (a-operand frag) ----
  auto influence = [&](int pl, float kx, float ky, float kz) -> half8 {
    float hk = kx * kx + ky * ky + kz * kz;
    half8 a0;
    #pragma unroll
    for (int j = 0; j < 8; ++j) {
      int a = quad * 8 + j;
      float4 q = np4[pl][a];
      float dt = q.x * kx + q.y * ky + q.z * kz;
      float d2 = fmaxf(q.w + hk - 2.f * dt, 0.f);
      a0[j] = (_Float16)fmaxf(1.f - 2.f * sqrtf(d2), 0.f);
    }
    return a0;
  };

  // ---- rank-2 influence (nbr 32,33) at kp=me, redistributed to k=quad*4+r ----
  auto rank2 = [&](int pl, float kx, float ky, float kz, float* w32r, float* w33r) {
    float hk = kx * kx + ky * ky + kz * kz;
    float4 q = np4[pl][32];
    float dt = q.x * kx + q.y * ky + q.z * kz;
    float w32 = fmaxf(1.f - 2.f * sqrtf(fmaxf(q.w + hk - 2.f * dt, 0.f)), 0.f);
    q = np4[pl][33];
    dt = q.x * kx + q.y * ky + q.z * kz;
    float w33 = fmaxf(1.f - 2.f * sqrtf(fmaxf(q.w + hk - 2.f * dt, 0.f)), 0.f);
    #pragma unroll
    for (int r = 0; r < 4; ++r) {
      int src = (quad * 4 + r) << 2;
      w32r[r] = __int_as_float(__builtin_amdgcn_ds_bpermute(src, __float_as_int(w32)));
      w33r[r] = __int_as_float(__builtin_amdgcn_ds_bpermute(src, __float_as_int(w33)));
    }
  };

  // ---- read one B-fragment from fTw (rotation must match transpose_g) ----
  auto read_bfrag = [&](int ct) -> half8 {
    int c  = ct * 16 + mm;
    int f  = ((c & 7) << 3) | (c >> 3);
    int pc = quad ^ (((c >> 3) ^ c) & 3);
    return *(const half8*)(fTw + f * 32 + pc * 8);
  };

  // ---- 2 MFMAs (cts ctbase,ctbase+1) + rank-2 fixup + mod, write wfh ----
  auto mfma_fix_write = [&](int pl, const half8& a0, const half8* bfr2, int ctbase,
                            const float* w32r, const float* w33r, const float* md) {
    #pragma unroll
    for (int t = 0; t < 2; ++t) {
      int c = (ctbase + t) * 16 + mm;
      floatx4 acc = __builtin_amdgcn_mfma_f32_16x16x32_f16(a0, bfr2[t], fz, 0, 0, 0);
      uint fp = fx2s[pl][c];
      float flo = (float)__builtin_bit_cast(_Float16, (unsigned short)(fp & 0xffffu));
      float fhi = (float)__builtin_bit_cast(_Float16, (unsigned short)(fp >> 16));
      half4 h;
      #pragma unroll
      for (int r = 0; r < 4; ++r)
        h[r] = (_Float16)((acc[r] + w32r[r] * flo + w33r[r] * fhi) * md[r]);
      *(half4*)(wfh + pl * 520 + (t * 16 + mm) * 16 + quad * 4) = h;
    }
  };

  // ---- half-K GEMM: 16 k-steps vs bmat rows [64][1024], offset 0 or 512 ----
  auto gemm_half = [&](const _Float16* bmat, int koff, floatx4& A, floatx4& B) {
    const _Float16* brow = bmat + (wave * 16 + mm) * 1024 + koff;
    const _Float16* arow = wfh + mm * 520;
    #pragma unroll
    for (int k2 = 0; k2 < 16; ++k2) {
      half8 af = *(const half8*)(arow + k2 * 32 + quad * 8);
      half8 bf = *(const half8*)(brow + k2 * 32 + quad * 8);
      if (k2 & 1) B = __builtin_amdgcn_mfma_f32_16x16x32_f16(af, bf, B, 0, 0, 0);
      else        A = __builtin_amdgcn_mfma_f32_16x16x32_f16(af, bf, A, 0, 0, 0);
    }
  };

  uint4 G0[2][2], G1[2][2];
  half8 bfr[4][4];          // B-fragments, live conv0 -> GEMM1 phase B
  half8 a0c[4];             // influence frags, live across current GEMM
  const float one4[4] = {1.f, 1.f, 1.f, 1.f};
  const float k0x = kpts[me * 3 + 0], k0y = kpts[me * 3 + 1], k0z = kpts[me * 3 + 2];

  // ================= conv0 (rigid kernel points): gather+transpose ONCE ======
  load_g(wave * 4, G0[0], G1[0]);
  #pragma unroll
  for (int pp = 0; pp < 4; ++pp) {
    int pl = wave * 4 + pp;
    if (pp < 3) load_g(pl + 1, G0[(pp + 1) & 1], G1[(pp + 1) & 1]);
    transpose_g(G0[pp & 1], G1[pp & 1]);
    a0c[pp] = influence(pl, k0x, k0y, k0z);
    float w32r[4], w33r[4];
    rank2(pl, k0x, k0y, k0z, w32r, w33r);
    #pragma unroll
    for (int ct = 0; ct < 4; ++ct) bfr[pp][ct] = read_bfrag(ct);
    mfma_fix_write(pl, a0c[pp], &bfr[pp][0], 0, w32r, w33r, one4);
  }
  __syncthreads();

  // ================= GEMM0 (2 phases; phase B recomputes ct2/3) ==============
  {
    floatx4 A = fz, B = fz;
    gemm_half(owt, 0, A, B);
    __syncthreads();
    #pragma unroll
    for (int pp = 0; pp < 4; ++pp) {
      int pl = wave * 4 + pp;
      float w32r[4], w33r[4];
      rank2(pl, k0x, k0y, k0z, w32r, w33r);
      mfma_fix_write(pl, a0c[pp], &bfr[pp][2], 2, w32r, w33r, one4);
    }
    __syncthreads();
    gemm_half(owt, 512, A, B);
    int d = wave * 16 + mm;
    float bv = (d < 60) ? obias[d] : 0.f;
    float kv = (d < 45) ? kpts[d] : 0.f;
    #pragma unroll
    for (int r = 0; r < 4; ++r) {
      int pt = quad * 4 + r;
      float v = A[r] + B[r] + bv;
      if (d < 60)
        dk[pt][d] = (d < 45) ? (kv + 0.5f * v)            // def_kp = kp + f0*EXTENT
                             : (2.f / (1.f + expf(-v)));  // modulation
    }
  }
  __syncthreads();   // dk ready; GEMM0 wfh reads done

  // ================= conv1 (deformed kps): pure register/LDS, NO gathers =====
  #pragma unroll
  for (int pp = 0; pp < 4; ++pp) {
    int pl = wave * 4 + pp;
    float kx = dk[pl][me * 3 + 0], ky = dk[pl][me * 3 + 1], kz = dk[pl][me * 3 + 2];
    float md[4];
    #pragma unroll
    for (int r = 0; r < 4; ++r) {
      int k = quad * 4 + r;
      int kk = (k < 15) ? k : 14;
      float t = dk[pl][45 + kk];
      md[r] = (k < 15) ? t : 1.f;
    }
    a0c[pp] = influence(pl, kx, ky, kz);
    float w32r[4], w33r[4];
    rank2(pl, kx, ky, kz, w32r, w33r);
    mfma_fix_write(pl, a0c[pp], &bfr[pp][0], 0, w32r, w33r, md);
  }
  __syncthreads();

  // ================= GEMM1 (2 phases) -> x + fused batch stats ===============
  {
    floatx4 A = fz, B = fz;
    gemm_half(wt, 0, A, B);
    __syncthreads();
    #pragma unroll
    for (int pp = 0; pp < 4; ++pp) {
      int pl = wave * 4 + pp;
      float kx = dk[pl][me * 3 + 0], ky = dk[pl][me * 3 + 1], kz = dk[pl][me * 3 + 2];
      float md[4];
      #pragma unroll
      for (int r = 0; r < 4; ++r) {
        int k = quad * 4 + r;
        int kk = (k < 15) ? k : 14;
        float t = dk[pl][45 + kk];
        md[r] = (k < 15) ? t : 1.f;
      }
      float w32r[4], w33r[4];
      rank2(pl, kx, ky, kz, w32r, w33r);
      mfma_fix_write(pl, a0c[pp], &bfr[pp][2], 2, w32r, w33r, md);
    }
    __syncthreads();
    gemm_half(wt, 512, A, B);
    int d = wave * 16 + mm;
    float s1 = 0.f, s2 = 0.f;
    #pragma unroll
    for (int r = 0; r < 4; ++r) {
      float v = A[r] + B[r];
      outx[(base + quad * 4 + r) * 64 + d] = v;
      s1 += v; s2 += v * v;
    }
    s1 += __shfl_xor(s1, 16); s2 += __shfl_xor(s2, 16);
    s1 += __shfl_xor(s1, 32); s2 += __shfl_xor(s2, 32);
    if (lane < 16) {
      atomicAdd(&stats[d], s1);
      atomicAdd(&stats[64 + d], s2);
    }
  }
}

// ---------------------------------------------------------------------------
// BN (batch stats, biased var, eps=1e-6) + LeakyReLU(0.1), in-place
// ---------------------------------------------------------------------------
__global__ __launch_bounds__(256) void k_norm(
    float* __restrict__ x, const float* __restrict__ stats,
    const float* __restrict__ gamma, const float* __restrict__ beta)
{
  const int i = blockIdx.x * 256 + threadIdx.x;
  float4 v = ((float4*)x)[i];
  const int c0 = (i * 4) & 63;
  float o[4] = {v.x, v.y, v.z, v.w};
  #pragma unroll
  for (int j = 0; j < 4; ++j) {
    int c = c0 + j;
    float mean = stats[c] * (1.f / NPTS);
    float var  = stats[64 + c] * (1.f / NPTS) - mean * mean;
    float s = rsqrtf(var + 1e-6f) * gamma[c];
    float y = (o[j] - mean) * s + beta[c];
    o[j] = (y >= 0.f) ? y : 0.1f * y;
  }
  float4 rv = {o[0], o[1], o[2], o[3]};
  ((float4*)x)[i] = rv;
}

// ---------------------------------------------------------------------------
extern "C" void kernel_launch(void* const* d_in, const int* in_sizes, int n_in,
                              void* d_out, int out_size, void* d_ws, size_t ws_size,
                              hipStream_t stream)
{
  const float* query   = (const float*)d_in[0];
  const float* support = (const float*)d_in[1];
  const int*   nidx    = (const int*)d_in[2];
  const float* feat    = (const float*)d_in[3];
  const float* weight  = (const float*)d_in[4];
  const float* oweight = (const float*)d_in[5];
  const float* obias   = (const float*)d_in[6];
  const float* gamma   = (const float*)d_in[7];
  const float* beta    = (const float*)d_in[8];
  const float* kpts    = (const float*)d_in[9];
  float* x = (float*)d_out;

  char* ws = (char*)d_ws;
  _Float16* featH = (_Float16*)ws;                  // 8,388,608 B
  _Float16* owt   = (_Float16*)(ws + 8388608);      //   131,072 B
  _Float16* wt    = (_Float16*)(ws + 8519680);      //   131,072 B
  float*    stats = (float*)(ws + 8650752);         //       512 B

  k_prep<<<4352, 256, 0, stream>>>(oweight, weight, feat, owt, wt, featH, stats);
  k_fused<<<4096, 256, 0, stream>>>(query, support, nidx, featH, kpts, obias,
                                    owt, wt, x, stats);
  k_norm<<<4096, 256, 0, stream>>>(x, stats, gamma, beta);
}

// Round 3
// 297.062 us; speedup vs baseline: 1.5664x; 1.1823x over previous
//
#include <hip/hip_runtime.h>
#include <math.h>

#define NPTS 65536

using half8   = __attribute__((ext_vector_type(8))) _Float16;
using half4   = __attribute__((ext_vector_type(4))) _Float16;
using floatx4 = __attribute__((ext_vector_type(4))) float;

// ---------------------------------------------------------------------------
// k_prep: weights -> f16 [64 d][1024 kc'] with kc' = c*16 + k (k=15 row zero);
//         features -> f16 table featH[N][64]. Block 0 also zeroes stats.
// ---------------------------------------------------------------------------
__global__ __launch_bounds__(256) void k_prep(
    const float* __restrict__ ow, const float* __restrict__ w,
    const float* __restrict__ feat,
    _Float16* __restrict__ owt, _Float16* __restrict__ wt,
    _Float16* __restrict__ featH, float* __restrict__ stats)
{
  int b = blockIdx.x;
  if (b < 256) {                       // 256*256 == 65536 == 64*1024
    int i = b * 256 + threadIdx.x;
    int d = i >> 10, kc = i & 1023, c = kc >> 4, k = kc & 15;
    owt[i] = (k < 15 && d < 60) ? (_Float16)ow[(k * 64 + c) * 60 + d] : (_Float16)0.f;
    wt[i]  = (k < 15) ? (_Float16)w[(k * 64 + c) * 64 + d] : (_Float16)0.f;
    if (b == 0 && threadIdx.x < 128) stats[threadIdx.x] = 0.f;
  } else {                             // 4096*256 == 1048576 == N*64/4
    int j = (b - 256) * 256 + threadIdx.x;
    float4 f = ((const float4*)feat)[j];
    half4 h = {(_Float16)f.x, (_Float16)f.y, (_Float16)f.z, (_Float16)f.w};
    ((half4*)featH)[j] = h;
  }
}

// ---------------------------------------------------------------------------
// Fused deformable KPConv. 16 pts/block, 4 waves x 4 pts. Round-0 structure
// (two gather passes, per-point transpose into fT, no reg-capping) with:
//  * quarter-K GEMM A-panel (wfh 8448 B) + deferred quarters held as PACKED
//    f16 half4 (24 regs, less than round-0's 32-reg floatx4 hold)
//    -> LDS 37312 B -> 4 blocks/CU at natural register allocation.
//  * rank-2 neighbors (32,33) folded into a second chained MFMA (a2/b2)
//    instead of 8 ds_bpermute + ~45 VALU per conv point; modulation folded
//    into the A-fragment (lane row == kernel point) so no acc fixup at all.
//  * batch stats fused into the GEMM1 epilogue (k_stats + memset gone).
// Round-1/2 lesson: no launch_bounds(256,4) (AGPR split -> 64-reg cap ->
// spills); (256,3) keeps the allocator honest, occupancy comes from LDS.
// ---------------------------------------------------------------------------
__global__ __launch_bounds__(256, 3) void k_fused(
    const float* __restrict__ query, const float* __restrict__ support,
    const int* __restrict__ nidx, const _Float16* __restrict__ featH,
    const float* __restrict__ kpts, const float* __restrict__ obias,
    const _Float16* __restrict__ owt, const _Float16* __restrict__ wt,
    float* __restrict__ outx, float* __restrict__ stats)
{
  __shared__ float                  npx[16][34], npy[16][34], npz[16][34]; // 6528B
  __shared__ unsigned short         sidx[16][34];    // 1088B
  __shared__ __align__(16) _Float16 fT[4][64 * 32];  // per-wave transpose 16384B
  __shared__ unsigned int           fx2[4][64];      // per-wave (f32,f33)/c 1024B
  __shared__ __align__(16) _Float16 wfh[16 * 264];   // quarter-K A-panel 8448B
  __shared__ float                  dk[16][60];      // def_kp(45)+mod(15) 3840B

  const int tid  = threadIdx.x;
  const int wave = tid >> 6, lane = tid & 63;
  const int quad = lane >> 4, mm = lane & 15;
  const int base = blockIdx.x * 16;
  _Float16* fTw = fT[wave];
  unsigned int* fTw32 = (unsigned int*)fTw;
  unsigned int* fx2w = fx2[wave];
  const floatx4 fz = {0.f, 0.f, 0.f, 0.f};
  const int me = (mm < 15) ? mm : 14;   // row 15 of conv A is discarded

  // ---- stage neighbor displacements + indices (all 34 real, no shadow) ----
  for (int s = tid; s < 544; s += 256) {
    int pt = s / 34, a = s - pt * 34;
    int n = base + pt;
    int id = nidx[n * 34 + a];
    npx[pt][a] = support[id * 3 + 0] - query[n * 3 + 0];
    npy[pt][a] = support[id * 3 + 1] - query[n * 3 + 1];
    npz[pt][a] = support[id * 3 + 2] - query[n * 3 + 2];
    sidx[pt][a] = (unsigned short)id;
  }
  __syncthreads();

  // ---- gather loads (17 row-pairs x 8 chunks = 136 tasks) ----
  auto load_g = [&](int pl, uint4* g0, uint4* g1) {
    #pragma unroll
    for (int it = 0; it < 3; ++it) {
      int task = it * 64 + lane;
      if (task < 136) {
        int rp = task >> 3, ch = task & 7;
        int i0 = (int)sidx[pl][2 * rp], i1 = (int)sidx[pl][2 * rp + 1];
        g0[it] = *(const uint4*)(featH + i0 * 64 + ch * 8);
        g1[it] = *(const uint4*)(featH + i1 * 64 + ch * 8);
      }
    }
  };
  // ---- transpose staged regs -> fTw (rp<16) / fx2w (rp==16) ----
  auto transpose_g = [&](const uint4* g0, const uint4* g1) {
    #pragma unroll
    for (int it = 0; it < 3; ++it) {
      int task = it * 64 + lane;
      if (task < 136) {
        int rp = task >> 3, ch = task & 7;
        const uint* p0 = (const uint*)&g0[it];
        const uint* p1 = (const uint*)&g1[it];
        if (rp < 16) {
          int chunk = rp >> 2, o = rp & 3;
          #pragma unroll
          for (int cc = 0; cc < 8; ++cc) {
            int c  = ch * 8 + cc;
            int pc = chunk ^ ((ch ^ cc) & 3);
            uint v = __builtin_amdgcn_perm(p1[cc >> 1], p0[cc >> 1],
                                           (cc & 1) ? 0x07060302u : 0x05040100u);
            fTw32[c * 16 + pc * 4 + o] = v;
          }
        } else {  // rows 32,33 -> fx2 (lo = f32[c], hi = f33[c])
          #pragma unroll
          for (int cc = 0; cc < 8; ++cc) {
            uint v = __builtin_amdgcn_perm(p1[cc >> 1], p0[cc >> 1],
                                           (cc & 1) ? 0x07060302u : 0x05040100u);
            fx2w[ch * 8 + cc] = v;
          }
        }
      }
    }
  };

  // ---- one conv point: 4x (MFMA nbr0..31 + chained rank-2 MFMA nbr32,33).
  //      modulation pre-folded into A rows (lane row == kernel point).
  //      writes ct0 quarter to wfh, returns ct1..3 packed in hq[3] ----
  auto conv_point = [&](int pl, float kx, float ky, float kz, float modme,
                        half4* hq) {
    half8 a0;
    #pragma unroll
    for (int j = 0; j < 8; ++j) {
      int a = quad * 8 + j;
      float dx = npx[pl][a] - kx, dy = npy[pl][a] - ky, dz = npz[pl][a] - kz;
      float wv = 1.f - 2.f * sqrtf(dx * dx + dy * dy + dz * dz);
      a0[j] = (_Float16)(fmaxf(wv, 0.f) * modme);
    }
    // rank-2 rows: virtual k'=0,1 supplied only by quad-0 lanes (row = mm)
    float dx = npx[pl][32] - kx, dy = npy[pl][32] - ky, dz = npz[pl][32] - kz;
    float w32 = fmaxf(1.f - 2.f * sqrtf(dx * dx + dy * dy + dz * dz), 0.f) * modme;
    dx = npx[pl][33] - kx; dy = npy[pl][33] - ky; dz = npz[pl][33] - kz;
    float w33 = fmaxf(1.f - 2.f * sqrtf(dx * dx + dy * dy + dz * dz), 0.f) * modme;
    half8 a2 = {};
    a2[0] = (_Float16)((quad == 0) ? w32 : 0.f);
    a2[1] = (_Float16)((quad == 0) ? w33 : 0.f);
    #pragma unroll
    for (int ct = 0; ct < 4; ++ct) {
      int c  = ct * 16 + mm;
      int pc = quad ^ (((c >> 3) ^ c) & 3);
      half8 b = *(const half8*)(fTw + c * 32 + pc * 8);
      floatx4 acc = __builtin_amdgcn_mfma_f32_16x16x32_f16(a0, b, fz, 0, 0, 0);
      uint fp = fx2w[c];
      half8 b2 = {};
      b2[0] = __builtin_bit_cast(_Float16, (unsigned short)(fp & 0xffffu));
      b2[1] = __builtin_bit_cast(_Float16, (unsigned short)(fp >> 16));
      acc = __builtin_amdgcn_mfma_f32_16x16x32_f16(a2, b2, acc, 0, 0, 0);
      half4 h = {(_Float16)acc[0], (_Float16)acc[1],
                 (_Float16)acc[2], (_Float16)acc[3]};
      if (ct == 0) *(half4*)(wfh + pl * 264 + mm * 16 + quad * 4) = h;
      else         hq[ct - 1] = h;
    }
  };

  // ---- write one held quarter (ct = idx+1) into wfh ----
  auto write_hold = [&](const half4 (*hq)[3], int idx) {
    #pragma unroll
    for (int pp = 0; pp < 4; ++pp)
      *(half4*)(wfh + (wave * 4 + pp) * 264 + mm * 16 + quad * 4) = hq[pp][idx];
  };

  // ---- quarter-K GEMM: 8 k-steps vs bmat rows [64][1024], quarter p ----
  auto gemm_q = [&](const _Float16* bmat, int p, floatx4& A, floatx4& B) {
    const _Float16* brow = bmat + (wave * 16 + mm) * 1024 + p * 256;
    const _Float16* arow = wfh + mm * 264;
    #pragma unroll
    for (int k2 = 0; k2 < 8; ++k2) {
      half8 af = *(const half8*)(arow + k2 * 32 + quad * 8);
      half8 bf = *(const half8*)(brow + k2 * 32 + quad * 8);
      if (k2 & 1) B = __builtin_amdgcn_mfma_f32_16x16x32_f16(af, bf, B, 0, 0, 0);
      else        A = __builtin_amdgcn_mfma_f32_16x16x32_f16(af, bf, A, 0, 0, 0);
    }
  };

  uint4 G0[2][3], G1[2][3];
  half4 hq[4][3];           // deferred quarters, packed f16 (24 VGPRs)
  const float k0x = kpts[me * 3 + 0], k0y = kpts[me * 3 + 1], k0z = kpts[me * 3 + 2];

  // ================= conv0 (rigid kernel points) =================
  {
    load_g(wave * 4, G0[0], G1[0]);
    #pragma unroll
    for (int pp = 0; pp < 4; ++pp) {
      int pl = wave * 4 + pp;
      if (pp < 3) load_g(pl + 1, G0[(pp + 1) & 1], G1[(pp + 1) & 1]);
      transpose_g(G0[pp & 1], G1[pp & 1]);
      conv_point(pl, k0x, k0y, k0z, 1.f, hq[pp]);
    }
  }
  load_g(wave * 4, G0[0], G1[0]);   // prefetch conv1 p0 under GEMM0
  __syncthreads();

  // ================= GEMM0 (4 quarter phases) -> def_kp + modulations ========
  {
    floatx4 A = fz, B = fz;
    gemm_q(owt, 0, A, B);
    __syncthreads(); write_hold(hq, 0); __syncthreads();
    gemm_q(owt, 1, A, B);
    __syncthreads(); write_hold(hq, 1); __syncthreads();
    gemm_q(owt, 2, A, B);
    __syncthreads(); write_hold(hq, 2); __syncthreads();
    gemm_q(owt, 3, A, B);
    int d = wave * 16 + mm;
    float bv = (d < 60) ? obias[d] : 0.f;
    float kv = (d < 45) ? kpts[d] : 0.f;
    #pragma unroll
    for (int r = 0; r < 4; ++r) {
      int pt = quad * 4 + r;
      float v = A[r] + B[r] + bv;
      if (d < 60)
        dk[pt][d] = (d < 45) ? (kv + 0.5f * v)            // def_kp = kp + f0*EXTENT
                             : (2.f / (1.f + expf(-v)));  // modulation
    }
  }
  __syncthreads();   // dk ready; GEMM0 wfh reads done

  // ================= conv1 (deformed kernel points) =================
  #pragma unroll
  for (int pp = 0; pp < 4; ++pp) {
    int pl = wave * 4 + pp;
    if (pp < 3) load_g(pl + 1, G0[(pp + 1) & 1], G1[(pp + 1) & 1]);
    float kx = dk[pl][me * 3 + 0], ky = dk[pl][me * 3 + 1], kz = dk[pl][me * 3 + 2];
    float modme = dk[pl][45 + me];
    transpose_g(G0[pp & 1], G1[pp & 1]);
    conv_point(pl, kx, ky, kz, modme, hq[pp]);
  }
  __syncthreads();

  // ================= GEMM1 (4 quarter phases) -> x + fused batch stats =======
  {
    floatx4 A = fz, B = fz;
    gemm_q(wt, 0, A, B);
    __syncthreads(); write_hold(hq, 0); __syncthreads();
    gemm_q(wt, 1, A, B);
    __syncthreads(); write_hold(hq, 1); __syncthreads();
    gemm_q(wt, 2, A, B);
    __syncthreads(); write_hold(hq, 2); __syncthreads();
    gemm_q(wt, 3, A, B);
    int d = wave * 16 + mm;
    float s1 = 0.f, s2 = 0.f;
    #pragma unroll
    for (int r = 0; r < 4; ++r) {
      float v = A[r] + B[r];
      outx[(base + quad * 4 + r) * 64 + d] = v;
      s1 += v; s2 += v * v;
    }
    s1 += __shfl_xor(s1, 16); s2 += __shfl_xor(s2, 16);
    s1 += __shfl_xor(s1, 32); s2 += __shfl_xor(s2, 32);
    if (lane < 16) {
      atomicAdd(&stats[d], s1);
      atomicAdd(&stats[64 + d], s2);
    }
  }
}

// ---------------------------------------------------------------------------
// BN (batch stats, biased var, eps=1e-6) + LeakyReLU(0.1), in-place
// ---------------------------------------------------------------------------
__global__ __launch_bounds__(256) void k_norm(
    float* __restrict__ x, const float* __restrict__ stats,
    const float* __restrict__ gamma, const float* __restrict__ beta)
{
  const int i = blockIdx.x * 256 + threadIdx.x;
  float4 v = ((float4*)x)[i];
  const int c0 = (i * 4) & 63;
  float o[4] = {v.x, v.y, v.z, v.w};
  #pragma unroll
  for (int j = 0; j < 4; ++j) {
    int c = c0 + j;
    float mean = stats[c] * (1.f / NPTS);
    float var  = stats[64 + c] * (1.f / NPTS) - mean * mean;
    float s = rsqrtf(var + 1e-6f) * gamma[c];
    float y = (o[j] - mean) * s + beta[c];
    o[j] = (y >= 0.f) ? y : 0.1f * y;
  }
  float4 rv = {o[0], o[1], o[2], o[3]};
  ((float4*)x)[i] = rv;
}

// ---------------------------------------------------------------------------
extern "C" void kernel_launch(void* const* d_in, const int* in_sizes, int n_in,
                              void* d_out, int out_size, void* d_ws, size_t ws_size,
                              hipStream_t stream)
{
  const float* query   = (const float*)d_in[0];
  const float* support = (const float*)d_in[1];
  const int*   nidx    = (const int*)d_in[2];
  const float* feat    = (const float*)d_in[3];
  const float* weight  = (const float*)d_in[4];
  const float* oweight = (const float*)d_in[5];
  const float* obias   = (const float*)d_in[6];
  const float* gamma   = (const float*)d_in[7];
  const float* beta    = (const float*)d_in[8];
  const float* kpts    = (const float*)d_in[9];
  float* x = (float*)d_out;

  char* ws = (char*)d_ws;
  _Float16* featH = (_Float16*)ws;                  // 8,388,608 B
  _Float16* owt   = (_Float16*)(ws + 8388608);      //   131,072 B
  _Float16* wt    = (_Float16*)(ws + 8519680);      //   131,072 B
  float*    stats = (float*)(ws + 8650752);         //       512 B

  k_prep<<<4352, 256, 0, stream>>>(oweight, weight, feat, owt, wt, featH, stats);
  k_fused<<<4096, 256, 0, stream>>>(query, support, nidx, featH, kpts, obias,
                                    owt, wt, x, stats);
  k_norm<<<4096, 256, 0, stream>>>(x, stats, gamma, beta);
}